// Round 4
// baseline (380.969 us; speedup 1.0000x reference)
//
#include <hip/hip_runtime.h>
#include <math.h>

#define GD 128        // dynamic/feature dim
#define NBW 2048      // bitmask words per table (covers N<=65536)

// ---------------- dependency-pruning infrastructure ----------------

// Wave-aggregated append: one atomic per wave. Must be called by ALL lanes
// of the wave (no divergent early-out above it); lane 0 is the leader.
__device__ __forceinline__ int wave_append(int pred, int* __restrict__ cnt) {
    unsigned long long mask = __ballot(pred);
    if (mask == 0ULL) return -1;   // uniform: ballot result identical across wave
    int lane = threadIdx.x & 63;
    int prefix = __popcll(mask & ((1ULL << lane) - 1ULL));
    int base = 0;
    if (lane == 0) base = atomicAdd(cnt, __popcll(mask));
    base = __shfl(base, 0, 64);
    return pred ? (base + prefix) : -1;
}

__global__ __launch_bounds__(256) void mark_codeids(const int* __restrict__ codeid, int B,
                                                    unsigned* __restrict__ bits) {
    int i = blockIdx.x * 256 + threadIdx.x;
    if (i < B) {
        int c = codeid[i];
        atomicOr(&bits[c >> 5], 1u << (c & 31));
    }
}

// Each thread handles 4 edges (one int4 of erow). If bitIn[erow] -> append edge
// to list and set bitOut[ecol]. Gather table is 7.5 KB -> L1-resident.
__global__ __launch_bounds__(256) void filter_edges_bits(const int4* __restrict__ erow4,
                                                         const int4* __restrict__ ecol4,
                                                         int E4, int E,
                                                         const unsigned* __restrict__ bitsIn,
                                                         unsigned* __restrict__ bitsOut,
                                                         int* __restrict__ list,
                                                         int* __restrict__ cnt) {
    int i = blockIdx.x * 256 + threadIdx.x;
    int4 er = make_int4(0, 0, 0, 0);
    int valid = (i < E4);
    if (valid) er = erow4[i];
    int base_e = i * 4;
    // 4 independent L1 gathers
    int p0 = 0, p1 = 0, p2 = 0, p3 = 0;
    if (valid) {
        p0 = (base_e + 0 < E) && ((bitsIn[er.x >> 5] >> (er.x & 31)) & 1u);
        p1 = (base_e + 1 < E) && ((bitsIn[er.y >> 5] >> (er.y & 31)) & 1u);
        p2 = (base_e + 2 < E) && ((bitsIn[er.z >> 5] >> (er.z & 31)) & 1u);
        p3 = (base_e + 3 < E) && ((bitsIn[er.w >> 5] >> (er.w & 31)) & 1u);
    }
    if (p0 | p1 | p2 | p3) {
        int4 ec = ecol4[i];
        if (p0) atomicOr(&bitsOut[ec.x >> 5], 1u << (ec.x & 31));
        if (p1) atomicOr(&bitsOut[ec.y >> 5], 1u << (ec.y & 31));
        if (p2) atomicOr(&bitsOut[ec.z >> 5], 1u << (ec.z & 31));
        if (p3) atomicOr(&bitsOut[ec.w >> 5], 1u << (ec.w & 31));
    }
    int q;
    q = wave_append(p0, cnt); if (q >= 0) list[q] = base_e + 0;
    q = wave_append(p1, cnt); if (q >= 0) list[q] = base_e + 1;
    q = wave_append(p2, cnt); if (q >= 0) list[q] = base_e + 2;
    q = wave_append(p3, cnt); if (q >= 0) list[q] = base_e + 3;
}

__global__ __launch_bounds__(256) void compact_rows(const unsigned* __restrict__ bits0,
                                                    const unsigned* __restrict__ bits1, int N,
                                                    int* __restrict__ rows0, int* __restrict__ cnt0,
                                                    int* __restrict__ rows1, int* __restrict__ cnt1) {
    int r = blockIdx.x * 256 + threadIdx.x;
    int p0 = 0, p1 = 0;
    if (r < N) {
        p0 = (bits0[r >> 5] >> (r & 31)) & 1u;
        p1 = (bits1[r >> 5] >> (r & 31)) & 1u;
    }
    int pos0 = wave_append(p0, cnt0);
    if (pos0 >= 0) rows0[pos0] = r;
    int pos1 = wave_append(p1, cnt1);
    if (pos1 >= 0) rows1[pos1] = r;
}

// ---------------- compute kernels (grid-stride, device-count driven) ----------------

// Y[rows[i]] = X[rows[i]] @ W for i < *cntp. 8 rows/block-iteration, 32 thr/row.
// In-place safe (X==Y): rows are staged into LDS before any store.
__global__ __launch_bounds__(256) void gemm_rows(const float* __restrict__ X,
                                                 const float* __restrict__ W,
                                                 float* __restrict__ Y,
                                                 const int* __restrict__ rows,
                                                 const int* __restrict__ cntp) {
    __shared__ float xs[8 * GD];
    __shared__ int rid[8];
    int t = threadIdx.x;
    int cnt = *cntp;
    int ngroups = (cnt + 7) >> 3;
    for (int g = blockIdx.x; g < ngroups; g += gridDim.x) {
        if (t < 8) {
            int gi = g * 8 + t;
            rid[t] = (gi < cnt) ? rows[gi] : -1;
        }
        __syncthreads();
        int r = rid[t >> 5];
        if (r >= 0) ((float4*)xs)[t] = ((const float4*)(X + (size_t)r * GD))[t & 31];
        __syncthreads();
        int c4 = (t & 31) * 4;
        const float* xrow = xs + (t >> 5) * GD;
        float a0 = 0.f, a1 = 0.f, a2 = 0.f, a3 = 0.f;
#pragma unroll 8
        for (int k = 0; k < GD; ++k) {
            float xv = xrow[k];
            float4 w = *(const float4*)(W + k * GD + c4);
            a0 += xv * w.x; a1 += xv * w.y; a2 += xv * w.z; a3 += xv * w.w;
        }
        if (r >= 0) *(float4*)(Y + (size_t)r * GD + c4) = make_float4(a0, a1, a2, a3);
        __syncthreads();
    }
}

__global__ __launch_bounds__(256) void zero_rows(float* __restrict__ buf,
                                                 const int* __restrict__ rows,
                                                 const int* __restrict__ cntp) {
    int cnt = *cntp;
    int total = cnt * 32;  // float4 per thread
    for (int i = blockIdx.x * 256 + threadIdx.x; i < total; i += gridDim.x * 256) {
        int r = rows[i >> 5];
        ((float4*)(buf + (size_t)r * GD))[i & 31] = make_float4(0.f, 0.f, 0.f, 0.f);
    }
}

__global__ __launch_bounds__(256) void zero_rows_n(float* __restrict__ buf,
                                                   const int* __restrict__ rows, int n) {
    int total = n * 32;
    for (int i = blockIdx.x * 256 + threadIdx.x; i < total; i += gridDim.x * 256) {
        int r = rows[i >> 5];
        ((float4*)(buf + (size_t)r * GD))[i & 31] = make_float4(0.f, 0.f, 0.f, 0.f);
    }
}

// agg[erow[e]][c] += S[ecol[e]][c] * ev[e] over filtered edge list
__global__ __launch_bounds__(256) void scatter_list(const float* __restrict__ S,
                                                    const int* __restrict__ list,
                                                    const int* __restrict__ cntp,
                                                    const int* __restrict__ erow,
                                                    const int* __restrict__ ecol,
                                                    const float* __restrict__ ev,
                                                    float* __restrict__ agg) {
    int cnt = *cntp;
    long long total = (long long)cnt * GD;
    for (long long i = (long long)blockIdx.x * 256 + threadIdx.x; i < total;
         i += (long long)gridDim.x * 256) {
        int e = list[(int)(i >> 7)];
        int c = (int)(i & 127);
        atomicAdd(agg + (size_t)erow[e] * GD + c, S[(size_t)ecol[e] * GD + c] * ev[e]);
    }
}

// out[rows[i]] = relu(0.1*agg[rows[i]] + 0.9*init[rows[i]])
__global__ __launch_bounds__(256) void blend_rows(const float* __restrict__ agg,
                                                  const float* __restrict__ init,
                                                  float* __restrict__ out,
                                                  const int* __restrict__ rows,
                                                  const int* __restrict__ cntp) {
    int cnt = *cntp;
    int total = cnt * 32;
    for (int i = blockIdx.x * 256 + threadIdx.x; i < total; i += gridDim.x * 256) {
        int r = rows[i >> 5];
        int c = i & 31;
        float4 a = ((const float4*)(agg + (size_t)r * GD))[c];
        float4 b = ((const float4*)(init + (size_t)r * GD))[c];
        float4 o;
        o.x = fmaxf(0.1f * a.x + 0.9f * b.x, 0.0f);
        o.y = fmaxf(0.1f * a.y + 0.9f * b.y, 0.0f);
        o.z = fmaxf(0.1f * a.z + 0.9f * b.z, 0.0f);
        o.w = fmaxf(0.1f * a.w + 0.9f * b.w, 0.0f);
        ((float4*)(out + (size_t)r * GD))[c] = o;
    }
}

// One block (128 threads) per output row b.
__global__ __launch_bounds__(128) void final_rnn(const float* __restrict__ agg2,
                                                 const float* __restrict__ init,
                                                 const float* __restrict__ patient,
                                                 const float* __restrict__ timediffs,
                                                 const float* __restrict__ features,
                                                 const float* __restrict__ W_ih,
                                                 const float* __restrict__ b_ih,
                                                 const float* __restrict__ W_hh,
                                                 const float* __restrict__ b_hh,
                                                 const int* __restrict__ codeid,
                                                 const int* __restrict__ patientid,
                                                 float* __restrict__ out) {
    __shared__ float in1[257];
    __shared__ float ce[GD];
    __shared__ float red[GD];
    int b = blockIdx.x;
    int j = threadIdx.x;
    int cid = codeid[b];
    int pid = patientid[0];

    ce[j] = fmaxf(0.1f * agg2[(size_t)cid * GD + j] + 0.9f * init[(size_t)cid * GD + j], 0.0f);
    in1[j] = patient[(size_t)pid * GD + j];
    in1[GD + 1 + j] = features[(size_t)b * GD + j];
    if (j == 0) in1[GD] = timediffs[b];
    __syncthreads();

    float acc = b_ih[j] + b_hh[j];
    const float* wih = W_ih + (size_t)j * 257;
#pragma unroll 8
    for (int k = 0; k < 257; ++k) acc += in1[k] * wih[k];
    const float* whh = W_hh + (size_t)j * GD;
#pragma unroll 8
    for (int k = 0; k < GD; ++k) acc += ce[k] * whh[k];
    float h = tanhf(acc);

    red[j] = h * h;
    __syncthreads();
    for (int s = 64; s > 0; s >>= 1) {
        if (j < s) red[j] += red[j + s];
        __syncthreads();
    }
    float nrm = fmaxf(sqrtf(red[0]), 1e-12f);
    out[(size_t)b * GD + j] = h / nrm;
}

extern "C" void kernel_launch(void* const* d_in, const int* in_sizes, int n_in,
                              void* d_out, int out_size, void* d_ws, size_t ws_size,
                              hipStream_t stream) {
    const float* code_dynamic = (const float*)d_in[0];
    const float* init_cd      = (const float*)d_in[1];
    const float* patient      = (const float*)d_in[2];
    const float* timediffs    = (const float*)d_in[3];
    const float* features     = (const float*)d_in[4];
    const float* edge_val     = (const float*)d_in[5];
    const float* W1           = (const float*)d_in[6];
    const float* W2           = (const float*)d_in[7];
    const float* W_ih         = (const float*)d_in[8];
    const float* b_ih         = (const float*)d_in[9];
    const float* W_hh         = (const float*)d_in[10];
    const float* b_hh         = (const float*)d_in[11];
    const int* edge_row       = (const int*)d_in[12];
    const int* edge_col       = (const int*)d_in[13];
    const int* codeid         = (const int*)d_in[14];
    const int* patientid      = (const int*)d_in[15];

    int N = in_sizes[0] / GD;   // 60000
    int E = in_sizes[5];        // 600000
    int B = in_sizes[14];       // 256
    size_t nd = (size_t)N * GD;

    // workspace layout
    float* bufA     = (float*)d_ws;          // support / x1   (N*128 f32)
    float* bufB     = bufA + nd;             // agg            (N*128 f32)
    int* list1      = (int*)(bufB + nd);     // E
    int* list2      = list1 + E;             // E
    unsigned* bits0 = (unsigned*)(list2 + E);// NBW  -- zeroed region starts here
    unsigned* bits1 = bits0 + NBW;           // NBW
    unsigned* bits2 = bits1 + NBW;           // NBW
    int* cnts       = (int*)(bits2 + NBW);   // 8: [cntE2, cntE1, cntR0, cntR1]
    int* rows0      = cnts + 8;              // N
    int* rows1      = rows0 + N;             // N

    // zero the three bit tables + counters (24.6 KB)
    hipMemsetAsync(bits0, 0, (3 * NBW + 8) * sizeof(int), stream);

    int E4 = (E + 3) / 4;
    int eb4 = (E4 + 255) / 256;
    int nb = (N + 255) / 256;

    // dependency cone: codeid rows -> edges2 -> needed1 rows -> edges1 -> needed0 rows
    mark_codeids<<<(B + 255) / 256, 256, 0, stream>>>(codeid, B, bits2);
    filter_edges_bits<<<eb4, 256, 0, stream>>>((const int4*)edge_row, (const int4*)edge_col,
                                               E4, E, bits2, bits1, list2, &cnts[0]);
    filter_edges_bits<<<eb4, 256, 0, stream>>>((const int4*)edge_row, (const int4*)edge_col,
                                               E4, E, bits1, bits0, list1, &cnts[1]);
    compact_rows<<<nb, 256, 0, stream>>>(bits0, bits1, N, rows0, &cnts[2], rows1, &cnts[3]);

    // layer 1 (only needed0 rows / edges1 / needed1 rows)
    gemm_rows<<<1024, 256, 0, stream>>>(code_dynamic, W1, bufA, rows0, &cnts[2]);
    zero_rows<<<256, 256, 0, stream>>>(bufB, rows1, &cnts[3]);
    scatter_list<<<2048, 256, 0, stream>>>(bufA, list1, &cnts[1], edge_row, edge_col, edge_val, bufB);
    blend_rows<<<256, 256, 0, stream>>>(bufB, init_cd, bufA, rows1, &cnts[3]);

    // layer 2 (only needed1 rows / edges2 / codeid rows)
    gemm_rows<<<1024, 256, 0, stream>>>(bufA, W2, bufA, rows1, &cnts[3]);  // in-place safe
    zero_rows_n<<<32, 256, 0, stream>>>(bufB, codeid, B);
    scatter_list<<<2048, 256, 0, stream>>>(bufA, list2, &cnts[0], edge_row, edge_col, edge_val, bufB);

    // RNNCell + L2 normalize
    final_rnn<<<B, 128, 0, stream>>>(bufB, init_cd, patient, timediffs, features,
                                     W_ih, b_ih, W_hh, b_hh, codeid, patientid,
                                     (float*)d_out);
}

// Round 5
// 376.870 us; speedup vs baseline: 1.0109x; 1.0109x over previous
//
#include <hip/hip_runtime.h>
#include <math.h>

#define GD 128        // dynamic/feature dim
#define NBW 2048      // bitmask words per table (covers N<=65536), 8 KB

// ---------------- dependency-pruning infrastructure ----------------

// Wave-aggregated append: one atomic per wave. Call from ALL lanes.
__device__ __forceinline__ int wave_append(int pred, int* __restrict__ cnt) {
    unsigned long long mask = __ballot(pred);
    if (mask == 0ULL) return -1;   // uniform across the wave
    int lane = threadIdx.x & 63;
    int prefix = __popcll(mask & ((1ULL << lane) - 1ULL));
    int base = 0;
    if (lane == 0) base = atomicAdd(cnt, __popcll(mask));
    base = __shfl(base, 0, 64);
    return pred ? (base + prefix) : -1;
}

// Single block: zero all three bit tables + counters, then mark codeid bits.
__global__ __launch_bounds__(256) void init_and_mark(unsigned* __restrict__ bits0,
                                                     const int* __restrict__ codeid, int B) {
    int t = threadIdx.x;
    // zero 3*NBW words + 8 counter ints (contiguous)
    for (int k = t; k < 3 * NBW + 8; k += 256) bits0[k] = 0u;
    __syncthreads();
    unsigned* bits2 = bits0 + 2 * NBW;
    for (int i = t; i < B; i += 256) {
        int c = codeid[i];
        atomicOr(&bits2[c >> 5], 1u << (c & 31));
    }
}

// Each thread handles 4 edges (one int4 of erow). Bitmap staged in LDS:
// divergent gathers hit LDS (32 banks/cy) instead of the global path
// (~100 cyc/lane serialized — measured R2/R3/R4 all at 103 µs).
__global__ __launch_bounds__(256) void filter_edges_lds(const int4* __restrict__ erow4,
                                                        const int4* __restrict__ ecol4,
                                                        int E4, int E,
                                                        const unsigned* __restrict__ bitsIn,
                                                        unsigned* __restrict__ bitsOut,
                                                        int* __restrict__ list,
                                                        int* __restrict__ cnt) {
    __shared__ unsigned lb[NBW];
    int t = threadIdx.x;
    ((uint4*)lb)[t]       = ((const uint4*)bitsIn)[t];
    ((uint4*)lb)[t + 256] = ((const uint4*)bitsIn)[t + 256];
    __syncthreads();

    int i = blockIdx.x * 256 + t;
    int4 er = make_int4(0, 0, 0, 0);
    int valid = (i < E4);
    if (valid) er = erow4[i];
    int base_e = i * 4;
    int p0 = 0, p1 = 0, p2 = 0, p3 = 0;
    if (valid) {
        p0 = (base_e + 0 < E) && ((lb[er.x >> 5] >> (er.x & 31)) & 1u);
        p1 = (base_e + 1 < E) && ((lb[er.y >> 5] >> (er.y & 31)) & 1u);
        p2 = (base_e + 2 < E) && ((lb[er.z >> 5] >> (er.z & 31)) & 1u);
        p3 = (base_e + 3 < E) && ((lb[er.w >> 5] >> (er.w & 31)) & 1u);
    }
    if (p0 | p1 | p2 | p3) {
        int4 ec = ecol4[i];
        if (p0) atomicOr(&bitsOut[ec.x >> 5], 1u << (ec.x & 31));
        if (p1) atomicOr(&bitsOut[ec.y >> 5], 1u << (ec.y & 31));
        if (p2) atomicOr(&bitsOut[ec.z >> 5], 1u << (ec.z & 31));
        if (p3) atomicOr(&bitsOut[ec.w >> 5], 1u << (ec.w & 31));
    }
    int q;
    q = wave_append(p0, cnt); if (q >= 0) list[q] = base_e + 0;
    q = wave_append(p1, cnt); if (q >= 0) list[q] = base_e + 1;
    q = wave_append(p2, cnt); if (q >= 0) list[q] = base_e + 2;
    q = wave_append(p3, cnt); if (q >= 0) list[q] = base_e + 3;
}

__global__ __launch_bounds__(256) void compact_rows(const unsigned* __restrict__ bits0,
                                                    const unsigned* __restrict__ bits1, int N,
                                                    int* __restrict__ rows0, int* __restrict__ cnt0,
                                                    int* __restrict__ rows1, int* __restrict__ cnt1) {
    int r = blockIdx.x * 256 + threadIdx.x;
    int p0 = 0, p1 = 0;
    if (r < N) {
        p0 = (bits0[r >> 5] >> (r & 31)) & 1u;   // coalesced: 64 lanes share 2 words
        p1 = (bits1[r >> 5] >> (r & 31)) & 1u;
    }
    int pos0 = wave_append(p0, cnt0);
    if (pos0 >= 0) rows0[pos0] = r;
    int pos1 = wave_append(p1, cnt1);
    if (pos1 >= 0) rows1[pos1] = r;
}

// ---------------- compute kernels (grid-stride, device-count driven) ----------------

// Y[rows[i]] = stage(rows[i]) @ W for i < *cntp.
// stage = X[r] if blendInit==null else relu(0.1*X[r] + 0.9*blendInit[r]).
// 8 rows/block-iteration, 32 thr/row, rows staged in LDS (in-place safe).
__global__ __launch_bounds__(256) void gemm_rows(const float* __restrict__ X,
                                                 const float* __restrict__ blendInit,
                                                 const float* __restrict__ W,
                                                 float* __restrict__ Y,
                                                 const int* __restrict__ rows,
                                                 const int* __restrict__ cntp) {
    __shared__ float xs[8 * GD];
    __shared__ int rid[8];
    int t = threadIdx.x;
    int cnt = *cntp;
    int ngroups = (cnt + 7) >> 3;
    for (int g = blockIdx.x; g < ngroups; g += gridDim.x) {
        if (t < 8) {
            int gi = g * 8 + t;
            rid[t] = (gi < cnt) ? rows[gi] : -1;
        }
        __syncthreads();
        int r = rid[t >> 5];
        if (r >= 0) {
            float4 v = ((const float4*)(X + (size_t)r * GD))[t & 31];
            if (blendInit) {
                float4 b = ((const float4*)(blendInit + (size_t)r * GD))[t & 31];
                v.x = fmaxf(0.1f * v.x + 0.9f * b.x, 0.0f);
                v.y = fmaxf(0.1f * v.y + 0.9f * b.y, 0.0f);
                v.z = fmaxf(0.1f * v.z + 0.9f * b.z, 0.0f);
                v.w = fmaxf(0.1f * v.w + 0.9f * b.w, 0.0f);
            }
            ((float4*)xs)[t] = v;
        }
        __syncthreads();
        int c4 = (t & 31) * 4;
        const float* xrow = xs + (t >> 5) * GD;
        float a0 = 0.f, a1 = 0.f, a2 = 0.f, a3 = 0.f;
#pragma unroll 8
        for (int k = 0; k < GD; ++k) {
            float xv = xrow[k];
            float4 w = *(const float4*)(W + k * GD + c4);
            a0 += xv * w.x; a1 += xv * w.y; a2 += xv * w.z; a3 += xv * w.w;
        }
        if (r >= 0) *(float4*)(Y + (size_t)r * GD + c4) = make_float4(a0, a1, a2, a3);
        __syncthreads();
    }
}

__global__ __launch_bounds__(256) void zero_rows(float* __restrict__ buf,
                                                 const int* __restrict__ rows,
                                                 const int* __restrict__ cntp) {
    int cnt = *cntp;
    int total = cnt * 32;  // float4 per thread
    for (int i = blockIdx.x * 256 + threadIdx.x; i < total; i += gridDim.x * 256) {
        int r = rows[i >> 5];
        ((float4*)(buf + (size_t)r * GD))[i & 31] = make_float4(0.f, 0.f, 0.f, 0.f);
    }
}

__global__ __launch_bounds__(256) void zero_rows_n(float* __restrict__ buf,
                                                   const int* __restrict__ rows, int n) {
    int total = n * 32;
    for (int i = blockIdx.x * 256 + threadIdx.x; i < total; i += gridDim.x * 256) {
        int r = rows[i >> 5];
        ((float4*)(buf + (size_t)r * GD))[i & 31] = make_float4(0.f, 0.f, 0.f, 0.f);
    }
}

// agg[erow[e]][c] += S[ecol[e]][c] * ev[e] over filtered edge list.
// A wave covers 64 consecutive columns of one edge: all accesses coalesced,
// edge metadata loads are wave-uniform broadcasts.
__global__ __launch_bounds__(256) void scatter_list(const float* __restrict__ S,
                                                    const int* __restrict__ list,
                                                    const int* __restrict__ cntp,
                                                    const int* __restrict__ erow,
                                                    const int* __restrict__ ecol,
                                                    const float* __restrict__ ev,
                                                    float* __restrict__ agg) {
    int cnt = *cntp;
    long long total = (long long)cnt * GD;
    for (long long i = (long long)blockIdx.x * 256 + threadIdx.x; i < total;
         i += (long long)gridDim.x * 256) {
        int e = list[(int)(i >> 7)];
        int c = (int)(i & 127);
        atomicAdd(agg + (size_t)erow[e] * GD + c, S[(size_t)ecol[e] * GD + c] * ev[e]);
    }
}

// One block (128 threads) per output row b.
__global__ __launch_bounds__(128) void final_rnn(const float* __restrict__ agg2,
                                                 const float* __restrict__ init,
                                                 const float* __restrict__ patient,
                                                 const float* __restrict__ timediffs,
                                                 const float* __restrict__ features,
                                                 const float* __restrict__ W_ih,
                                                 const float* __restrict__ b_ih,
                                                 const float* __restrict__ W_hh,
                                                 const float* __restrict__ b_hh,
                                                 const int* __restrict__ codeid,
                                                 const int* __restrict__ patientid,
                                                 float* __restrict__ out) {
    __shared__ float in1[257];
    __shared__ float ce[GD];
    __shared__ float red[GD];
    int b = blockIdx.x;
    int j = threadIdx.x;
    int cid = codeid[b];
    int pid = patientid[0];

    ce[j] = fmaxf(0.1f * agg2[(size_t)cid * GD + j] + 0.9f * init[(size_t)cid * GD + j], 0.0f);
    in1[j] = patient[(size_t)pid * GD + j];
    in1[GD + 1 + j] = features[(size_t)b * GD + j];
    if (j == 0) in1[GD] = timediffs[b];
    __syncthreads();

    float acc = b_ih[j] + b_hh[j];
    const float* wih = W_ih + (size_t)j * 257;
#pragma unroll 8
    for (int k = 0; k < 257; ++k) acc += in1[k] * wih[k];
    const float* whh = W_hh + (size_t)j * GD;
#pragma unroll 8
    for (int k = 0; k < GD; ++k) acc += ce[k] * whh[k];
    float h = tanhf(acc);

    red[j] = h * h;
    __syncthreads();
    for (int s = 64; s > 0; s >>= 1) {
        if (j < s) red[j] += red[j + s];
        __syncthreads();
    }
    float nrm = fmaxf(sqrtf(red[0]), 1e-12f);
    out[(size_t)b * GD + j] = h / nrm;
}

extern "C" void kernel_launch(void* const* d_in, const int* in_sizes, int n_in,
                              void* d_out, int out_size, void* d_ws, size_t ws_size,
                              hipStream_t stream) {
    const float* code_dynamic = (const float*)d_in[0];
    const float* init_cd      = (const float*)d_in[1];
    const float* patient      = (const float*)d_in[2];
    const float* timediffs    = (const float*)d_in[3];
    const float* features     = (const float*)d_in[4];
    const float* edge_val     = (const float*)d_in[5];
    const float* W1           = (const float*)d_in[6];
    const float* W2           = (const float*)d_in[7];
    const float* W_ih         = (const float*)d_in[8];
    const float* b_ih         = (const float*)d_in[9];
    const float* W_hh         = (const float*)d_in[10];
    const float* b_hh         = (const float*)d_in[11];
    const int* edge_row       = (const int*)d_in[12];
    const int* edge_col       = (const int*)d_in[13];
    const int* codeid         = (const int*)d_in[14];
    const int* patientid      = (const int*)d_in[15];

    int N = in_sizes[0] / GD;   // 60000
    int E = in_sizes[5];        // 600000
    int B = in_sizes[14];       // 256
    size_t nd = (size_t)N * GD;

    // workspace layout
    float* bufA     = (float*)d_ws;           // support  (N*128 f32)
    float* bufB     = bufA + nd;              // agg      (N*128 f32)
    int* list1      = (int*)(bufB + nd);      // E
    int* list2      = list1 + E;              // E
    unsigned* bits0 = (unsigned*)(list2 + E); // NBW ┐ zeroed by init_and_mark
    unsigned* bits1 = bits0 + NBW;            // NBW │
    unsigned* bits2 = bits1 + NBW;            // NBW │
    int* cnts       = (int*)(bits2 + NBW);    // 8   ┘ [cntE2, cntE1, cntR0, cntR1]
    int* rows0      = cnts + 8;               // N
    int* rows1      = rows0 + N;              // N

    int E4 = (E + 3) / 4;
    int eb4 = (E4 + 255) / 256;
    int nb = (N + 255) / 256;

    // dependency cone: codeid rows -> edges2 -> needed1 rows -> edges1 -> needed0 rows
    init_and_mark<<<1, 256, 0, stream>>>(bits0, codeid, B);
    filter_edges_lds<<<eb4, 256, 0, stream>>>((const int4*)edge_row, (const int4*)edge_col,
                                              E4, E, bits2, bits1, list2, &cnts[0]);
    filter_edges_lds<<<eb4, 256, 0, stream>>>((const int4*)edge_row, (const int4*)edge_col,
                                              E4, E, bits1, bits0, list1, &cnts[1]);
    compact_rows<<<nb, 256, 0, stream>>>(bits0, bits1, N, rows0, &cnts[2], rows1, &cnts[3]);

    // layer 1 (only needed0 rows / edges1 / needed1 rows)
    gemm_rows<<<1024, 256, 0, stream>>>(code_dynamic, nullptr, W1, bufA, rows0, &cnts[2]);
    zero_rows<<<256, 256, 0, stream>>>(bufB, rows1, &cnts[3]);
    scatter_list<<<2048, 256, 0, stream>>>(bufA, list1, &cnts[1], edge_row, edge_col, edge_val, bufB);

    // layer 2 (blend fused into gemm staging; only needed1 rows / edges2 / codeid rows)
    gemm_rows<<<1024, 256, 0, stream>>>(bufB, init_cd, W2, bufA, rows1, &cnts[3]);
    zero_rows_n<<<32, 256, 0, stream>>>(bufB, codeid, B);
    scatter_list<<<2048, 256, 0, stream>>>(bufA, list2, &cnts[0], edge_row, edge_col, edge_val, bufB);

    // RNNCell + L2 normalize
    final_rnn<<<B, 128, 0, stream>>>(bufB, init_cd, patient, timediffs, features,
                                     W_ih, b_ih, W_hh, b_hh, codeid, patientid,
                                     (float*)d_out);
}